// Round 1
// baseline (2529.057 us; speedup 1.0000x reference)
//
#include <hip/hip_runtime.h>
#include <cstdint>
#include <cstddef>

// GraphResBlock2 on MI355X — round 5: edge-parallel gather + LDS f32 atomic
// accumulation + B-fragments direct from L2 (no Bs staging, no per-kk barriers).
// CSR is TYPE-MAJOR (seg = type*N + row) so each 64-row tile's edges per type
// are contiguous -> lanes split edges evenly (Poisson(64)/64 trips instead of
// max-of-16-Poisson(1) divergent walks). Local row packed into pcol bits 17..22.
// Workspace identical to round-4 (~115 MB proven envelope).
// N=100000, E=700000, C1=128, C2=256, 7 edge types.

#define N_ET 7

typedef __bf16 bf16;
typedef __bf16 bf16x8 __attribute__((ext_vector_type(8)));
typedef __bf16 bf16x4 __attribute__((ext_vector_type(4)));
typedef float f32x4v __attribute__((ext_vector_type(4)));

// ---------------- CSR build (type-major: seg = et*N + row) ----------------

__global__ void count_edges_k(const int* __restrict__ row, const int* __restrict__ et,
                              int* __restrict__ cnt, int E, int N) {
  int e = blockIdx.x * 256 + threadIdx.x;
  if (e < E) atomicAdd(&cnt[et[e] * N + row[e]], 1);
}

__global__ void inv_counts_k(const int* __restrict__ cnt, float* __restrict__ inv, int n) {
  int i = blockIdx.x * 256 + threadIdx.x;
  if (i < n) inv[i] = 1.0f / fmaxf((float)cnt[i], 1.0f);
}

__global__ __launch_bounds__(1024) void scan1_k(const int* __restrict__ cnt,
                                                int* __restrict__ off,
                                                int* __restrict__ bsum, int n) {
  __shared__ int s[1024];
  int tid = threadIdx.x;
  int i = blockIdx.x * 1024 + tid;
  int v = (i < n) ? cnt[i] : 0;
  s[tid] = v;
  __syncthreads();
  for (int d = 1; d < 1024; d <<= 1) {
    int t = (tid >= d) ? s[tid - d] : 0;
    __syncthreads();
    s[tid] += t;
    __syncthreads();
  }
  if (i < n) off[i] = s[tid] - v;
  if (tid == 1023) bsum[blockIdx.x] = s[1023];
}

__global__ __launch_bounds__(1024) void scan2_k(int* __restrict__ bsum, int nb) {
  __shared__ int s[1024];
  int tid = threadIdx.x;
  int v = (tid < nb) ? bsum[tid] : 0;
  s[tid] = v;
  __syncthreads();
  for (int d = 1; d < 1024; d <<= 1) {
    int t = (tid >= d) ? s[tid - d] : 0;
    __syncthreads();
    s[tid] += t;
    __syncthreads();
  }
  if (tid < nb) bsum[tid] = s[tid] - v;
}

__global__ __launch_bounds__(1024) void scan3_k(int* __restrict__ off,
                                                const int* __restrict__ bsum,
                                                int n, int total) {
  int i = blockIdx.x * 1024 + threadIdx.x;
  if (i < n) off[i] += bsum[blockIdx.x];
  if (i == 0) off[n] = total;
}

// pk[pos] = col | ((row & 63) << 17)  — col < 2^17, local row (tiles are
// 64-aligned) in bits 17..22. Zero extra workspace vs plain pcol.
__global__ void place_k(const int* __restrict__ row, const int* __restrict__ col,
                        const int* __restrict__ et, const int* __restrict__ off,
                        int* __restrict__ cur, int* __restrict__ pk, int E, int N) {
  int e = blockIdx.x * 256 + threadIdx.x;
  if (e >= E) return;
  int r = row[e];
  int seg = et[e] * N + r;
  int pos = off[seg] + atomicAdd(&cur[seg], 1);
  pk[pos] = col[e] | ((r & 63) << 17);
}

// ---------------- weight transposes ----------------
// panel layout: Bt8[k>>3][col][k&7]  (16B per (k-panel, col))
__global__ void transpose_w8_k(const float* __restrict__ W, bf16* __restrict__ Bt8, int K) {
  int i = blockIdx.x * 256 + threadIdx.x;
  if (i < K * 256) {
    int k = i >> 8, col = i & 255;
    Bt8[((size_t)(k >> 3) * 256 + col) * 8 + (k & 7)] = (bf16)W[i];
  }
}

// old layout for the shortcut kernel: Bt[col][k]
__global__ void transpose_w_k(const float* __restrict__ W, bf16* __restrict__ Bt, int K) {
  int i = blockIdx.x * 256 + threadIdx.x;
  if (i < K * 256) {
    int k = i >> 8, n = i & 255;
    Bt[(size_t)n * K + k] = (bf16)W[i];
  }
}

// ---------------- fused-v3: edge-parallel aggregate + GEMM ----------------
// Cout[M,256] (bf16) = Aeff[M, 7*CW] @ W,
//   Aeff[m, type*CW + c] = inv[type*M+m] * sum_{p in seg(type,m)} X[pcol[p], c]
// Tile: 64 rows x 256 cols, 4 waves (2x2 -> 32 rows x 128 cols each).
// K in 128-wide sections. Per section:
//   zero f32 As -> edge-parallel gather (lane = edge slot, wave = 32-ch slice)
//   with ds_add_f32 accumulation (inv folded in) -> 4 kk MFMA iters reading
//   A-frags from LDS (cvt f32->bf16) and B-frags DIRECTLY from L2-resident Bt8.
// No per-kk barriers; 3 barriers/section total. LDS 34 KB -> 4 blocks/CU.
template <int CW, typename XT>
__launch_bounds__(256, 4)
__global__ void agg_gemm3_k(const XT* __restrict__ X, const bf16* __restrict__ Bt8,
                            const int* __restrict__ off, const int* __restrict__ pk,
                            const float* __restrict__ inv, bf16* __restrict__ Cout,
                            int M) {
  __shared__ alignas(16) float As[64][132];   // stride 132: 528B rows, 16B-aligned,
                                              // 2-way LDS banking (free per m136)
  __shared__ float invs[64];

  const int t = threadIdx.x;
  const int m0 = blockIdx.x * 64;
  const int lane = t & 63, w = t >> 6;
  const int wm = (w >> 1) * 32;
  const int wn = (w & 1) * 128;
  const int l15 = lane & 15, quad = lane >> 4;

  f32x4v acc[2][8];
#pragma unroll
  for (int i = 0; i < 2; ++i)
#pragma unroll
    for (int j = 0; j < 8; ++j) acc[i][j] = (f32x4v){0.f, 0.f, 0.f, 0.f};

  const int NSEC = (N_ET * CW) / 128;
  const int mh = (M - m0 < 64) ? (M - m0) : 64;

  for (int sec = 0; sec < NSEC; ++sec) {
    const int type = (CW == 128) ? sec : (sec >> 1);
    const int xb = ((sec * 128) & (CW - 1)) + w * 32;   // this wave's X column base

    __syncthreads();                     // (b0) prior section's As frag reads done
    {
      // zero: lane owns row `lane`, wave owns its 32-col slice -> conflict-free
      float4 z = make_float4(0.f, 0.f, 0.f, 0.f);
#pragma unroll
      for (int s2 = 0; s2 < 8; ++s2)
        *(float4*)&As[lane][w * 32 + s2 * 4] = z;
      if (t < 64) invs[t] = (t < mh) ? inv[(size_t)type * M + m0 + t] : 0.f;
    }
    __syncthreads();                     // (b1) As zeroed, invs staged

    {
      // type-major CSR: all edges of this type for rows [m0, m0+mh) contiguous
      const int base = type * M + m0;
      const int pS = off[base];
      const int pE = off[base + mh];
      for (int p = pS + lane; p < pE; p += 64) {
        const int u = pk[p];
        const int c = u & 131071;
        const int rl = u >> 17;
        const float iv = invs[rl];
        if constexpr (sizeof(XT) == 4) {
          const float* xp = (const float*)X + (size_t)c * CW + xb;
          const int rot = lane & 7;      // stagger group order: lanes hitting the
                                         // same row collide on addr only 1/8 of steps
#pragma unroll
          for (int g = 0; g < 8; ++g) {
            const int gg = ((g + rot) & 7) * 4;
            const float4 v = *(const float4*)(xp + gg);
            float* ap = &As[rl][w * 32 + gg];
            atomicAdd(ap + 0, v.x * iv);
            atomicAdd(ap + 1, v.y * iv);
            atomicAdd(ap + 2, v.z * iv);
            atomicAdd(ap + 3, v.w * iv);
          }
        } else {
          const bf16* xp = (const bf16*)X + (size_t)c * CW + xb;
          const int rot = lane & 3;
#pragma unroll
          for (int g = 0; g < 4; ++g) {
            const int gg = ((g + rot) & 3) * 8;
            const bf16x8 v = *(const bf16x8*)(xp + gg);
            float* ap = &As[rl][w * 32 + gg];
#pragma unroll
            for (int i = 0; i < 8; ++i)
              atomicAdd(ap + i, (float)v[i] * iv);
          }
        }
      }
    }
    __syncthreads();                     // (b2) atomics visible

    // ---- 4 k-iters; B frags straight from L2 (Bt8 is 0.46/0.9 MB, L2-resident)
#pragma unroll
    for (int kk = 0; kk < 4; ++kk) {
      const int k8b = sec * 16 + kk * 4;
      const bf16* bp = Bt8 + (size_t)(k8b + quad) * (256 * 8);
      bf16x8 bfr[8];
#pragma unroll
      for (int g = 0; g < 8; ++g)
        bfr[g] = *(const bf16x8*)(bp + (wn + g * 16 + l15) * 8);
      bf16x8 af[2];
#pragma unroll
      for (int f = 0; f < 2; ++f) {
        const float* ap = &As[wm + f * 16 + l15][kk * 32 + quad * 8];
        f32x4v a0 = *(const f32x4v*)ap;
        f32x4v a1 = *(const f32x4v*)(ap + 4);
        bf16x8 o;
        o[0] = (bf16)a0[0]; o[1] = (bf16)a0[1]; o[2] = (bf16)a0[2]; o[3] = (bf16)a0[3];
        o[4] = (bf16)a1[0]; o[5] = (bf16)a1[1]; o[6] = (bf16)a1[2]; o[7] = (bf16)a1[3];
        af[f] = o;
      }
#pragma unroll
      for (int fi = 0; fi < 2; ++fi)
#pragma unroll
        for (int fj = 0; fj < 8; ++fj)
          acc[fi][fj] = __builtin_amdgcn_mfma_f32_16x16x32_bf16(af[fi], bfr[fj], acc[fi][fj], 0, 0, 0);
    }
  }

  // ---- epilogue: bf16 store ----
#pragma unroll
  for (int fi = 0; fi < 2; ++fi) {
    int rbase = m0 + wm + fi * 16 + quad * 4;
#pragma unroll
    for (int rr = 0; rr < 4; ++rr) {
      int rowg = rbase + rr;
      if (rowg < M) {
#pragma unroll
        for (int fj = 0; fj < 8; ++fj)
          Cout[(size_t)rowg * 256 + wn + fj * 16 + l15] = (bf16)acc[fi][fj][rr];
      }
    }
  }
}

// ---------------- shortcut dense GEMM (unchanged, proven) ----------------
__launch_bounds__(256, 2)
__global__ void sc_gemm_k(const float* __restrict__ X, const bf16* __restrict__ Bt,
                          float* __restrict__ Cout, int M, int K) {
  __shared__ alignas(16) bf16 As[128][40];
  __shared__ alignas(16) bf16 Bs[256][40];
  const int t = threadIdx.x;
  const int m0 = blockIdx.x * 128;
  const int lane = t & 63, w = t >> 6;
  const int wm = (w >> 1) * 64;
  const int wn = (w & 1) * 128;
  const int l15 = lane & 15, quad = lane >> 4;

  f32x4v acc[4][8];
#pragma unroll
  for (int i = 0; i < 4; ++i)
#pragma unroll
    for (int j = 0; j < 8; ++j) acc[i][j] = (f32x4v){0.f, 0.f, 0.f, 0.f};

  const int r = t >> 1, h = t & 1;
  const int m = m0 + r;
  const bool mv = (m < M);

  for (int k0 = 0; k0 < K; k0 += 32) {
    const float* xp = X + (size_t)m * K + k0 + h * 16;
    float4 v0, v1, v2, v3;
    if (mv) {
      v0 = *(const float4*)(xp + 0);
      v1 = *(const float4*)(xp + 4);
      v2 = *(const float4*)(xp + 8);
      v3 = *(const float4*)(xp + 12);
    } else {
      v0 = v1 = v2 = v3 = make_float4(0.f, 0.f, 0.f, 0.f);
    }
    bf16x8 o0, o1;
    o0[0] = (bf16)v0.x; o0[1] = (bf16)v0.y; o0[2] = (bf16)v0.z; o0[3] = (bf16)v0.w;
    o0[4] = (bf16)v1.x; o0[5] = (bf16)v1.y; o0[6] = (bf16)v1.z; o0[7] = (bf16)v1.w;
    o1[0] = (bf16)v2.x; o1[1] = (bf16)v2.y; o1[2] = (bf16)v2.z; o1[3] = (bf16)v2.w;
    o1[4] = (bf16)v3.x; o1[5] = (bf16)v3.y; o1[6] = (bf16)v3.z; o1[7] = (bf16)v3.w;
    *(bf16x8*)&As[r][h * 16] = o0;
    *(bf16x8*)&As[r][h * 16 + 8] = o1;
    {
      const bf16* bp = Bt + (size_t)t * K + k0;
      bf16x8 b0 = *(const bf16x8*)(bp + 0);
      bf16x8 b1 = *(const bf16x8*)(bp + 8);
      bf16x8 b2 = *(const bf16x8*)(bp + 16);
      bf16x8 b3 = *(const bf16x8*)(bp + 24);
      *(bf16x8*)&Bs[t][0] = b0;
      *(bf16x8*)&Bs[t][8] = b1;
      *(bf16x8*)&Bs[t][16] = b2;
      *(bf16x8*)&Bs[t][24] = b3;
    }
    __syncthreads();
    bf16x8 af[4], bfr[8];
#pragma unroll
    for (int f = 0; f < 4; ++f) af[f] = *(const bf16x8*)&As[wm + f * 16 + l15][quad * 8];
#pragma unroll
    for (int g = 0; g < 8; ++g) bfr[g] = *(const bf16x8*)&Bs[wn + g * 16 + l15][quad * 8];
#pragma unroll
    for (int fi = 0; fi < 4; ++fi)
#pragma unroll
      for (int fj = 0; fj < 8; ++fj)
        acc[fi][fj] = __builtin_amdgcn_mfma_f32_16x16x32_bf16(af[fi], bfr[fj], acc[fi][fj], 0, 0, 0);
    __syncthreads();
  }

#pragma unroll
  for (int fi = 0; fi < 4; ++fi) {
    int rbase = m0 + wm + fi * 16 + quad * 4;
#pragma unroll
    for (int rr = 0; rr < 4; ++rr) {
      int rowg = rbase + rr;
      if (rowg < M) {
#pragma unroll
        for (int fj = 0; fj < 8; ++fj)
          Cout[(size_t)rowg * 256 + wn + fj * 16 + l15] = acc[fi][fj][rr];
      }
    }
  }
}

// ---------------- BN stats / params / elementwise ----------------

__global__ void colstats_bf16_k(const bf16* __restrict__ v, int N,
                                float* __restrict__ s, float* __restrict__ q) {
  int c = threadIdx.x;
  float a = 0.f, b = 0.f;
  for (int r = blockIdx.x; r < N; r += gridDim.x) {
    float x = (float)v[(size_t)r * 256 + c];
    a += x;
    b += x * x;
  }
  unsafeAtomicAdd(&s[c], a);
  unsafeAtomicAdd(&q[c], b);
}

__global__ void colstats_f32_k(const float* __restrict__ v, int N,
                               float* __restrict__ s, float* __restrict__ q) {
  int c = threadIdx.x;
  float a = 0.f, b = 0.f;
  for (int r = blockIdx.x; r < N; r += gridDim.x) {
    float x = v[(size_t)r * 256 + c];
    a += x;
    b += x * x;
  }
  unsafeAtomicAdd(&s[c], a);
  unsafeAtomicAdd(&q[c], b);
}

__global__ void bn_params_k(const float* __restrict__ s, const float* __restrict__ q,
                            const float* __restrict__ g, const float* __restrict__ b,
                            float* __restrict__ scale, float* __restrict__ shift, float invN) {
  int c = threadIdx.x;
  float m = s[c] * invN;
  float var = fmaxf(q[c] * invN - m * m, 0.f);
  float sc = g[c] * rsqrtf(var + 1e-5f);
  scale[c] = sc;
  shift[c] = b[c] - m * sc;
}

__global__ void bn_relu_ip_k(bf16* __restrict__ v, const float* __restrict__ scale,
                             const float* __restrict__ shift, int total8) {
  int i = blockIdx.x * 256 + threadIdx.x;
  if (i >= total8) return;
  size_t base = (size_t)i * 8;
  int c = (int)(base & 255);
  bf16x8 x = *(const bf16x8*)(v + base);
#pragma unroll
  for (int j = 0; j < 8; ++j)
    x[j] = (bf16)fmaxf((float)x[j] * scale[c + j] + shift[c + j], 0.f);
  *(bf16x8*)(v + base) = x;
}

__global__ void final_out_k(const bf16* __restrict__ cb,
                            const float* __restrict__ scB, const float* __restrict__ shB,
                            const float* __restrict__ scS, const float* __restrict__ shS,
                            float* __restrict__ out, int total4) {
  int i = blockIdx.x * 256 + threadIdx.x;
  if (i >= total4) return;
  size_t base = (size_t)i * 4;
  int c = (int)(base & 255);
  bf16x4 vb = *(const bf16x4*)(cb + base);
  float4 vs = *(const float4*)(out + base);
  float4 r;
  r.x = fmaxf((float)vb[0] * scB[c + 0] + shB[c + 0] + vs.x * scS[c + 0] + shS[c + 0], 0.f);
  r.y = fmaxf((float)vb[1] * scB[c + 1] + shB[c + 1] + vs.y * scS[c + 1] + shS[c + 1], 0.f);
  r.z = fmaxf((float)vb[2] * scB[c + 2] + shB[c + 2] + vs.z * scS[c + 2] + shS[c + 2], 0.f);
  r.w = fmaxf((float)vb[3] * scB[c + 3] + shB[c + 3] + vs.w * scS[c + 3] + shS[c + 3], 0.f);
  *(float4*)(out + base) = r;
}

__global__ void sentinel_k(float* __restrict__ out, int n) {
  int i = blockIdx.x * 256 + threadIdx.x;
  if (i < n) out[i] = 12345.0f;
}

// ---------------- launch ----------------

extern "C" void kernel_launch(void* const* d_in, const int* in_sizes, int n_in,
                              void* d_out, int out_size, void* d_ws, size_t ws_size,
                              hipStream_t stream) {
  const float* x  = (const float*)d_in[0];
  const int* ei   = (const int*)d_in[1];
  const int* etp  = (const int*)d_in[2];
  const float* Wa = (const float*)d_in[4];
  const float* ga = (const float*)d_in[5];
  const float* ba = (const float*)d_in[6];
  const float* Wb = (const float*)d_in[7];
  const float* gb = (const float*)d_in[8];
  const float* bb = (const float*)d_in[9];
  const float* W1 = (const float*)d_in[10];
  const float* g1 = (const float*)d_in[11];
  const float* b1 = (const float*)d_in[12];

  const int C1 = 128, C2 = 256;
  const int N = in_sizes[0] / C1;   // 100000
  const int E = in_sizes[2];        // 700000
  const int* row = ei;
  const int* col = ei + E;
  const int NS = N * N_ET;
  const int KA = N_ET * C1;         // 896
  const int KB = N_ET * C2;         // 1792

  size_t need = 0;
  auto alloc = [&](size_t bytes) { size_t o = need; need += (bytes + 15) & ~(size_t)15; return o; };
  char* w = (char*)d_ws;
  int*   off_p = (int*)(w + alloc(((size_t)NS + 1) * 4));
  int*   cnt_p = (int*)(w + alloc((size_t)NS * 4));
  int*   pk_p  = (int*)(w + alloc((size_t)E * 4));
  float* inv_p = (float*)(w + alloc((size_t)NS * 4));
  int*   bsum  = (int*)(w + alloc(1024 * 4));
  bf16*  Bt8A  = (bf16*)(w + alloc((size_t)KA * 256 * 2));
  bf16*  Bt8B  = (bf16*)(w + alloc((size_t)KB * 256 * 2));
  bf16*  Bt1   = (bf16*)(w + alloc((size_t)256 * C1 * 2));
  bf16*  x1    = (bf16*)(w + alloc((size_t)N * C2 * 2));
  bf16*  convb = (bf16*)(w + alloc((size_t)N * C2 * 2));
  float* st    = (float*)(w + alloc(12 * 256 * 4));

  if (ws_size < need) {
    sentinel_k<<<(out_size + 255) / 256, 256, 0, stream>>>((float*)d_out, out_size);
    return;
  }

  float* sum_a = st + 0 * 256, *ssq_a = st + 1 * 256;
  float* sum_b = st + 2 * 256, *ssq_b = st + 3 * 256;
  float* sum_s = st + 4 * 256, *ssq_s = st + 5 * 256;
  float* scA = st + 6 * 256, *shA = st + 7 * 256;
  float* scB = st + 8 * 256, *shB = st + 9 * 256;
  float* scS = st + 10 * 256, *shS = st + 11 * 256;

  const float invN = 1.0f / (float)N;
  const int nscan = (NS + 1023) / 1024;
  const int g2 = (N + 63) / 64;          // fused-v3 grid (64-row tiles)
  const int gsc = (N + 127) / 128;       // shortcut grid
  const int total8 = N * C2 / 8;
  const int total4 = N * C2 / 4;

  // --- CSR build (type-major) ---
  hipMemsetAsync(cnt_p, 0, (size_t)NS * 4, stream);
  hipMemsetAsync(st, 0, 12 * 256 * 4, stream);
  count_edges_k<<<(E + 255) / 256, 256, 0, stream>>>(row, etp, cnt_p, E, N);
  inv_counts_k<<<(NS + 255) / 256, 256, 0, stream>>>(cnt_p, inv_p, NS);
  scan1_k<<<nscan, 1024, 0, stream>>>(cnt_p, off_p, bsum, NS);
  scan2_k<<<1, 1024, 0, stream>>>(bsum, nscan);
  scan3_k<<<nscan, 1024, 0, stream>>>(off_p, bsum, NS, E);
  hipMemsetAsync(cnt_p, 0, (size_t)NS * 4, stream);
  place_k<<<(E + 255) / 256, 256, 0, stream>>>(row, col, etp, off_p, cnt_p, pk_p, E, N);

  // --- weight transposes ---
  transpose_w8_k<<<(KA * 256 + 255) / 256, 256, 0, stream>>>(Wa, Bt8A, KA);
  transpose_w8_k<<<(KB * 256 + 255) / 256, 256, 0, stream>>>(Wb, Bt8B, KB);
  transpose_w_k<<<(C1 * 256 + 255) / 256, 256, 0, stream>>>(W1, Bt1, C1);

  // --- conv_a: fused-v3 -> x1 (pre-BN bf16), then BN+ReLU in place ---
  agg_gemm3_k<128, float><<<g2, 256, 0, stream>>>(x, Bt8A, off_p, pk_p, inv_p, x1, N);
  colstats_bf16_k<<<512, 256, 0, stream>>>(x1, N, sum_a, ssq_a);
  bn_params_k<<<1, 256, 0, stream>>>(sum_a, ssq_a, ga, ba, scA, shA, invN);
  bn_relu_ip_k<<<(total8 + 255) / 256, 256, 0, stream>>>(x1, scA, shA, total8);

  // --- shortcut: x @ W1 -> d_out (f32) ---
  sc_gemm_k<<<gsc, 256, 0, stream>>>(x, Bt1, (float*)d_out, N, C1);
  colstats_f32_k<<<512, 256, 0, stream>>>((const float*)d_out, N, sum_s, ssq_s);
  bn_params_k<<<1, 256, 0, stream>>>(sum_s, ssq_s, g1, b1, scS, shS, invN);

  // --- conv_b: fused-v3 from x1 -> convb (pre-BN bf16) ---
  agg_gemm3_k<256, bf16><<<g2, 256, 0, stream>>>(x1, Bt8B, off_p, pk_p, inv_p, convb, N);
  colstats_bf16_k<<<512, 256, 0, stream>>>(convb, N, sum_b, ssq_b);
  bn_params_k<<<1, 256, 0, stream>>>(sum_b, ssq_b, gb, bb, scB, shB, invN);

  // --- out = relu(bn(convb) + bn(scp)) ---
  final_out_k<<<(total4 + 255) / 256, 256, 0, stream>>>(
      convb, scB, shB, scS, shS, (float*)d_out, total4);
}

// Round 2
// 1347.748 us; speedup vs baseline: 1.8765x; 1.8765x over previous
//
#include <hip/hip_runtime.h>
#include <cstdint>
#include <cstddef>

// GraphResBlock2 on MI355X — round 6: round-4 structure (proven 918 µs) with
// ONE change to the fused kernel: B fragments read directly from L2-resident
// Bt8 (no Bs LDS staging). Barriers per 128-wide K-section: 9 -> 2.
// LDS 33.8 KB -> 17.4 KB, __launch_bounds__(256,4) -> ~2x occupancy.
// Aggregation stays the proven serial per-thread segment walk (+pcol prefetch).
// N=100000, E=700000, C1=128, C2=256, 7 edge types.

#define N_ET 7

typedef __bf16 bf16;
typedef __bf16 bf16x8 __attribute__((ext_vector_type(8)));
typedef __bf16 bf16x4 __attribute__((ext_vector_type(4)));
typedef float f32x4v __attribute__((ext_vector_type(4)));

// ---------------- CSR build (row-major: seg = row*7 + et, as round 4) --------

__global__ void count_edges_k(const int* __restrict__ row, const int* __restrict__ et,
                              int* __restrict__ cnt, int E) {
  int e = blockIdx.x * 256 + threadIdx.x;
  if (e < E) atomicAdd(&cnt[row[e] * N_ET + et[e]], 1);
}

__global__ void inv_counts_k(const int* __restrict__ cnt, float* __restrict__ inv, int n) {
  int i = blockIdx.x * 256 + threadIdx.x;
  if (i < n) inv[i] = 1.0f / fmaxf((float)cnt[i], 1.0f);
}

__global__ __launch_bounds__(1024) void scan1_k(const int* __restrict__ cnt,
                                                int* __restrict__ off,
                                                int* __restrict__ bsum, int n) {
  __shared__ int s[1024];
  int tid = threadIdx.x;
  int i = blockIdx.x * 1024 + tid;
  int v = (i < n) ? cnt[i] : 0;
  s[tid] = v;
  __syncthreads();
  for (int d = 1; d < 1024; d <<= 1) {
    int t = (tid >= d) ? s[tid - d] : 0;
    __syncthreads();
    s[tid] += t;
    __syncthreads();
  }
  if (i < n) off[i] = s[tid] - v;
  if (tid == 1023) bsum[blockIdx.x] = s[1023];
}

__global__ __launch_bounds__(1024) void scan2_k(int* __restrict__ bsum, int nb) {
  __shared__ int s[1024];
  int tid = threadIdx.x;
  int v = (tid < nb) ? bsum[tid] : 0;
  s[tid] = v;
  __syncthreads();
  for (int d = 1; d < 1024; d <<= 1) {
    int t = (tid >= d) ? s[tid - d] : 0;
    __syncthreads();
    s[tid] += t;
    __syncthreads();
  }
  if (tid < nb) bsum[tid] = s[tid] - v;
}

__global__ __launch_bounds__(1024) void scan3_k(int* __restrict__ off,
                                                const int* __restrict__ bsum,
                                                int n, int total) {
  int i = blockIdx.x * 1024 + threadIdx.x;
  if (i < n) off[i] += bsum[blockIdx.x];
  if (i == 0) off[n] = total;
}

__global__ void place_k(const int* __restrict__ row, const int* __restrict__ col,
                        const int* __restrict__ et, const int* __restrict__ off,
                        int* __restrict__ cur, int* __restrict__ pcol, int E) {
  int e = blockIdx.x * 256 + threadIdx.x;
  if (e >= E) return;
  int seg = row[e] * N_ET + et[e];
  int pos = off[seg] + atomicAdd(&cur[seg], 1);
  pcol[pos] = col[e];
}

// ---------------- weight transposes ----------------
// panel layout: Bt8[k>>3][col][k&7]  (16B per (k-panel, col))
__global__ void transpose_w8_k(const float* __restrict__ W, bf16* __restrict__ Bt8, int K) {
  int i = blockIdx.x * 256 + threadIdx.x;
  if (i < K * 256) {
    int k = i >> 8, col = i & 255;
    Bt8[((size_t)(k >> 3) * 256 + col) * 8 + (k & 7)] = (bf16)W[i];
  }
}

// old layout for the shortcut kernel: Bt[col][k]
__global__ void transpose_w_k(const float* __restrict__ W, bf16* __restrict__ Bt, int K) {
  int i = blockIdx.x * 256 + threadIdx.x;
  if (i < K * 256) {
    int k = i >> 8, n = i & 255;
    Bt[(size_t)n * K + k] = (bf16)W[i];
  }
}

// ---------------- fused-v4: section-hoisted aggregate + GEMM, B from L2 ------
// Cout[M,256] (bf16) = Aeff[M, 7*CW] @ W, where
//   Aeff[m, type*CW + c] = inv[m*7+type] * sum_{p in seg(m,type)} X[pcol[p], c]
// Tile: 64 rows x 256 cols, 4 waves (2x2 -> 32 rows x 128 cols each).
// K processed in 128-wide sections; aggregation hoisted once per section
// (thread (r = t>>2, h = t&3) aggregates 32 channels of row r).
// B fragments are read DIRECTLY from L2-resident Bt8 per MFMA (no Bs staging,
// no per-kk barriers): 2 barriers per section total.
template <int CW, typename XT>
__launch_bounds__(256, 4)
__global__ void agg_gemm4_k(const XT* __restrict__ X, const bf16* __restrict__ Bt8,
                            const int* __restrict__ off, const int* __restrict__ pcol,
                            const float* __restrict__ inv, bf16* __restrict__ Cout,
                            int M) {
  __shared__ alignas(16) bf16 As[64][136];          // 64 rows x 128-col section (+8 pad)

  const int t = threadIdx.x;
  const int m0 = blockIdx.x * 64;
  const int lane = t & 63, w = t >> 6;
  const int wm = (w >> 1) * 32;
  const int wn = (w & 1) * 128;
  const int l15 = lane & 15, quad = lane >> 4;

  const int r = t >> 2, h = t & 3;                  // agg mapping
  const int m = m0 + r;
  const bool mv = (m < M);

  f32x4v acc[2][8];
#pragma unroll
  for (int i = 0; i < 2; ++i)
#pragma unroll
    for (int j = 0; j < 8; ++j) acc[i][j] = (f32x4v){0.f, 0.f, 0.f, 0.f};

  const int NSEC = (N_ET * CW) / 128;

  for (int sec = 0; sec < NSEC; ++sec) {
    // ---- aggregate this thread's (row, 32-channel) slice of the section ----
    const int type = (CW == 128) ? sec : (sec >> 1);
    const int xcol = ((sec * 128) & (CW - 1)) + h * 32;  // column base in X
    int sS = 0, sE = 0;
    float sc = 0.f;
    if (mv) {
      int seg = m * N_ET + type;
      sS = off[seg];
      sE = off[seg + 1];
      sc = inv[seg];
    }
    float s[32];
#pragma unroll
    for (int j = 0; j < 32; ++j) s[j] = 0.f;
    // prefetch next pcol to overlap index load with X row loads
    int p = sS;
    int nc = (p < sE) ? pcol[p] : 0;
    while (p < sE) {
      const int cI = nc;
      if (p + 1 < sE) nc = pcol[p + 1];
      if constexpr (sizeof(XT) == 4) {
        const float* xp = (const float*)X + (size_t)cI * CW + xcol;
#pragma unroll
        for (int j = 0; j < 8; ++j) {
          float4 v = *(const float4*)(xp + j * 4);
          s[j * 4 + 0] += v.x; s[j * 4 + 1] += v.y;
          s[j * 4 + 2] += v.z; s[j * 4 + 3] += v.w;
        }
      } else {
        const bf16* xp = (const bf16*)X + (size_t)cI * CW + xcol;
#pragma unroll
        for (int j = 0; j < 4; ++j) {
          bf16x8 v = *(const bf16x8*)(xp + j * 8);
#pragma unroll
          for (int i = 0; i < 8; ++i) s[j * 8 + i] += (float)v[i];
        }
      }
      ++p;
    }
    __syncthreads();   // (b1) all waves done reading previous As
#pragma unroll
    for (int j = 0; j < 4; ++j) {
      bf16x8 o;
#pragma unroll
      for (int i = 0; i < 8; ++i) o[i] = (bf16)(s[j * 8 + i] * sc);
      *(bf16x8*)&As[r][h * 32 + j * 8] = o;
    }
    __syncthreads();   // (b2) As visible to all waves

    // ---- 4 k-iters over this section; B frags straight from L2 ----
#pragma unroll
    for (int kk = 0; kk < 4; ++kk) {
      const int k8b = sec * 16 + kk * 4;
      const bf16* bp = Bt8 + (size_t)(k8b + quad) * (256 * 8);
      bf16x8 bfr[8];
#pragma unroll
      for (int g = 0; g < 8; ++g)
        bfr[g] = *(const bf16x8*)(bp + (size_t)(wn + g * 16 + l15) * 8);
      bf16x8 af[2];
#pragma unroll
      for (int f = 0; f < 2; ++f)
        af[f] = *(const bf16x8*)&As[wm + f * 16 + l15][kk * 32 + quad * 8];
#pragma unroll
      for (int fi = 0; fi < 2; ++fi)
#pragma unroll
        for (int fj = 0; fj < 8; ++fj)
          acc[fi][fj] = __builtin_amdgcn_mfma_f32_16x16x32_bf16(af[fi], bfr[fj], acc[fi][fj], 0, 0, 0);
    }
  }

  // ---- epilogue: bf16 store ----
#pragma unroll
  for (int fi = 0; fi < 2; ++fi) {
    int rbase = m0 + wm + fi * 16 + quad * 4;
#pragma unroll
    for (int rr = 0; rr < 4; ++rr) {
      int rowg = rbase + rr;
      if (rowg < M) {
#pragma unroll
        for (int fj = 0; fj < 8; ++fj)
          Cout[(size_t)rowg * 256 + wn + fj * 16 + l15] = (bf16)acc[fi][fj][rr];
      }
    }
  }
}

// ---------------- shortcut dense GEMM (round-2 tested, unchanged) ----------------
__launch_bounds__(256, 2)
__global__ void sc_gemm_k(const float* __restrict__ X, const bf16* __restrict__ Bt,
                          float* __restrict__ Cout, int M, int K) {
  __shared__ alignas(16) bf16 As[128][40];
  __shared__ alignas(16) bf16 Bs[256][40];
  const int t = threadIdx.x;
  const int m0 = blockIdx.x * 128;
  const int lane = t & 63, w = t >> 6;
  const int wm = (w >> 1) * 64;
  const int wn = (w & 1) * 128;
  const int l15 = lane & 15, quad = lane >> 4;

  f32x4v acc[4][8];
#pragma unroll
  for (int i = 0; i < 4; ++i)
#pragma unroll
    for (int j = 0; j < 8; ++j) acc[i][j] = (f32x4v){0.f, 0.f, 0.f, 0.f};

  const int r = t >> 1, h = t & 1;
  const int m = m0 + r;
  const bool mv = (m < M);

  for (int k0 = 0; k0 < K; k0 += 32) {
    const float* xp = X + (size_t)m * K + k0 + h * 16;
    float4 v0, v1, v2, v3;
    if (mv) {
      v0 = *(const float4*)(xp + 0);
      v1 = *(const float4*)(xp + 4);
      v2 = *(const float4*)(xp + 8);
      v3 = *(const float4*)(xp + 12);
    } else {
      v0 = v1 = v2 = v3 = make_float4(0.f, 0.f, 0.f, 0.f);
    }
    bf16x8 o0, o1;
    o0[0] = (bf16)v0.x; o0[1] = (bf16)v0.y; o0[2] = (bf16)v0.z; o0[3] = (bf16)v0.w;
    o0[4] = (bf16)v1.x; o0[5] = (bf16)v1.y; o0[6] = (bf16)v1.z; o0[7] = (bf16)v1.w;
    o1[0] = (bf16)v2.x; o1[1] = (bf16)v2.y; o1[2] = (bf16)v2.z; o1[3] = (bf16)v2.w;
    o1[4] = (bf16)v3.x; o1[5] = (bf16)v3.y; o1[6] = (bf16)v3.z; o1[7] = (bf16)v3.w;
    *(bf16x8*)&As[r][h * 16] = o0;
    *(bf16x8*)&As[r][h * 16 + 8] = o1;
    {
      const bf16* bp = Bt + (size_t)t * K + k0;
      bf16x8 b0 = *(const bf16x8*)(bp + 0);
      bf16x8 b1 = *(const bf16x8*)(bp + 8);
      bf16x8 b2 = *(const bf16x8*)(bp + 16);
      bf16x8 b3 = *(const bf16x8*)(bp + 24);
      *(bf16x8*)&Bs[t][0] = b0;
      *(bf16x8*)&Bs[t][8] = b1;
      *(bf16x8*)&Bs[t][16] = b2;
      *(bf16x8*)&Bs[t][24] = b3;
    }
    __syncthreads();
    bf16x8 af[4], bfr[8];
#pragma unroll
    for (int f = 0; f < 4; ++f) af[f] = *(const bf16x8*)&As[wm + f * 16 + l15][quad * 8];
#pragma unroll
    for (int g = 0; g < 8; ++g) bfr[g] = *(const bf16x8*)&Bs[wn + g * 16 + l15][quad * 8];
#pragma unroll
    for (int fi = 0; fi < 4; ++fi)
#pragma unroll
      for (int fj = 0; fj < 8; ++fj)
        acc[fi][fj] = __builtin_amdgcn_mfma_f32_16x16x32_bf16(af[fi], bfr[fj], acc[fi][fj], 0, 0, 0);
    __syncthreads();
  }

#pragma unroll
  for (int fi = 0; fi < 4; ++fi) {
    int rbase = m0 + wm + fi * 16 + quad * 4;
#pragma unroll
    for (int rr = 0; rr < 4; ++rr) {
      int rowg = rbase + rr;
      if (rowg < M) {
#pragma unroll
        for (int fj = 0; fj < 8; ++fj)
          Cout[(size_t)rowg * 256 + wn + fj * 16 + l15] = acc[fi][fj][rr];
      }
    }
  }
}

// ---------------- BN stats / params / elementwise ----------------

__global__ void colstats_bf16_k(const bf16* __restrict__ v, int N,
                                float* __restrict__ s, float* __restrict__ q) {
  int c = threadIdx.x;
  float a = 0.f, b = 0.f;
  for (int r = blockIdx.x; r < N; r += gridDim.x) {
    float x = (float)v[(size_t)r * 256 + c];
    a += x;
    b += x * x;
  }
  unsafeAtomicAdd(&s[c], a);
  unsafeAtomicAdd(&q[c], b);
}

__global__ void colstats_f32_k(const float* __restrict__ v, int N,
                               float* __restrict__ s, float* __restrict__ q) {
  int c = threadIdx.x;
  float a = 0.f, b = 0.f;
  for (int r = blockIdx.x; r < N; r += gridDim.x) {
    float x = v[(size_t)r * 256 + c];
    a += x;
    b += x * x;
  }
  unsafeAtomicAdd(&s[c], a);
  unsafeAtomicAdd(&q[c], b);
}

__global__ void bn_params_k(const float* __restrict__ s, const float* __restrict__ q,
                            const float* __restrict__ g, const float* __restrict__ b,
                            float* __restrict__ scale, float* __restrict__ shift, float invN) {
  int c = threadIdx.x;
  float m = s[c] * invN;
  float var = fmaxf(q[c] * invN - m * m, 0.f);
  float sc = g[c] * rsqrtf(var + 1e-5f);
  scale[c] = sc;
  shift[c] = b[c] - m * sc;
}

__global__ void bn_relu_ip_k(bf16* __restrict__ v, const float* __restrict__ scale,
                             const float* __restrict__ shift, int total8) {
  int i = blockIdx.x * 256 + threadIdx.x;
  if (i >= total8) return;
  size_t base = (size_t)i * 8;
  int c = (int)(base & 255);
  bf16x8 x = *(const bf16x8*)(v + base);
#pragma unroll
  for (int j = 0; j < 8; ++j)
    x[j] = (bf16)fmaxf((float)x[j] * scale[c + j] + shift[c + j], 0.f);
  *(bf16x8*)(v + base) = x;
}

__global__ void final_out_k(const bf16* __restrict__ cb,
                            const float* __restrict__ scB, const float* __restrict__ shB,
                            const float* __restrict__ scS, const float* __restrict__ shS,
                            float* __restrict__ out, int total4) {
  int i = blockIdx.x * 256 + threadIdx.x;
  if (i >= total4) return;
  size_t base = (size_t)i * 4;
  int c = (int)(base & 255);
  bf16x4 vb = *(const bf16x4*)(cb + base);
  float4 vs = *(const float4*)(out + base);
  float4 r;
  r.x = fmaxf((float)vb[0] * scB[c + 0] + shB[c + 0] + vs.x * scS[c + 0] + shS[c + 0], 0.f);
  r.y = fmaxf((float)vb[1] * scB[c + 1] + shB[c + 1] + vs.y * scS[c + 1] + shS[c + 1], 0.f);
  r.z = fmaxf((float)vb[2] * scB[c + 2] + shB[c + 2] + vs.z * scS[c + 2] + shS[c + 2], 0.f);
  r.w = fmaxf((float)vb[3] * scB[c + 3] + shB[c + 3] + vs.w * scS[c + 3] + shS[c + 3], 0.f);
  *(float4*)(out + base) = r;
}

__global__ void sentinel_k(float* __restrict__ out, int n) {
  int i = blockIdx.x * 256 + threadIdx.x;
  if (i < n) out[i] = 12345.0f;
}

// ---------------- launch ----------------

extern "C" void kernel_launch(void* const* d_in, const int* in_sizes, int n_in,
                              void* d_out, int out_size, void* d_ws, size_t ws_size,
                              hipStream_t stream) {
  const float* x  = (const float*)d_in[0];
  const int* ei   = (const int*)d_in[1];
  const int* etp  = (const int*)d_in[2];
  const float* Wa = (const float*)d_in[4];
  const float* ga = (const float*)d_in[5];
  const float* ba = (const float*)d_in[6];
  const float* Wb = (const float*)d_in[7];
  const float* gb = (const float*)d_in[8];
  const float* bb = (const float*)d_in[9];
  const float* W1 = (const float*)d_in[10];
  const float* g1 = (const float*)d_in[11];
  const float* b1 = (const float*)d_in[12];

  const int C1 = 128, C2 = 256;
  const int N = in_sizes[0] / C1;   // 100000
  const int E = in_sizes[2];        // 700000
  const int* row = ei;
  const int* col = ei + E;
  const int NS = N * N_ET;
  const int KA = N_ET * C1;         // 896
  const int KB = N_ET * C2;         // 1792

  size_t need = 0;
  auto alloc = [&](size_t bytes) { size_t o = need; need += (bytes + 15) & ~(size_t)15; return o; };
  char* w = (char*)d_ws;
  int*   off_p = (int*)(w + alloc(((size_t)NS + 1) * 4));
  int*   cnt_p = (int*)(w + alloc((size_t)NS * 4));
  int*   pcol  = (int*)(w + alloc((size_t)E * 4));
  float* inv_p = (float*)(w + alloc((size_t)NS * 4));
  int*   bsum  = (int*)(w + alloc(1024 * 4));
  bf16*  Bt8A  = (bf16*)(w + alloc((size_t)KA * 256 * 2));
  bf16*  Bt8B  = (bf16*)(w + alloc((size_t)KB * 256 * 2));
  bf16*  Bt1   = (bf16*)(w + alloc((size_t)256 * C1 * 2));
  bf16*  x1    = (bf16*)(w + alloc((size_t)N * C2 * 2));
  bf16*  convb = (bf16*)(w + alloc((size_t)N * C2 * 2));
  float* st    = (float*)(w + alloc(12 * 256 * 4));

  if (ws_size < need) {
    sentinel_k<<<(out_size + 255) / 256, 256, 0, stream>>>((float*)d_out, out_size);
    return;
  }

  float* sum_a = st + 0 * 256, *ssq_a = st + 1 * 256;
  float* sum_b = st + 2 * 256, *ssq_b = st + 3 * 256;
  float* sum_s = st + 4 * 256, *ssq_s = st + 5 * 256;
  float* scA = st + 6 * 256, *shA = st + 7 * 256;
  float* scB = st + 8 * 256, *shB = st + 9 * 256;
  float* scS = st + 10 * 256, *shS = st + 11 * 256;

  const float invN = 1.0f / (float)N;
  const int nscan = (NS + 1023) / 1024;
  const int g2 = (N + 63) / 64;          // fused grid (64-row tiles)
  const int gsc = (N + 127) / 128;       // shortcut grid
  const int total8 = N * C2 / 8;
  const int total4 = N * C2 / 4;

  // --- CSR build ---
  hipMemsetAsync(cnt_p, 0, (size_t)NS * 4, stream);
  hipMemsetAsync(st, 0, 12 * 256 * 4, stream);
  count_edges_k<<<(E + 255) / 256, 256, 0, stream>>>(row, etp, cnt_p, E);
  inv_counts_k<<<(NS + 255) / 256, 256, 0, stream>>>(cnt_p, inv_p, NS);
  scan1_k<<<nscan, 1024, 0, stream>>>(cnt_p, off_p, bsum, NS);
  scan2_k<<<1, 1024, 0, stream>>>(bsum, nscan);
  scan3_k<<<nscan, 1024, 0, stream>>>(off_p, bsum, NS, E);
  hipMemsetAsync(cnt_p, 0, (size_t)NS * 4, stream);
  place_k<<<(E + 255) / 256, 256, 0, stream>>>(row, col, etp, off_p, cnt_p, pcol, E);

  // --- weight transposes ---
  transpose_w8_k<<<(KA * 256 + 255) / 256, 256, 0, stream>>>(Wa, Bt8A, KA);
  transpose_w8_k<<<(KB * 256 + 255) / 256, 256, 0, stream>>>(Wb, Bt8B, KB);
  transpose_w_k<<<(C1 * 256 + 255) / 256, 256, 0, stream>>>(W1, Bt1, C1);

  // --- conv_a: fused-v4 -> x1 (pre-BN bf16), then BN+ReLU in place ---
  agg_gemm4_k<128, float><<<g2, 256, 0, stream>>>(x, Bt8A, off_p, pcol, inv_p, x1, N);
  colstats_bf16_k<<<512, 256, 0, stream>>>(x1, N, sum_a, ssq_a);
  bn_params_k<<<1, 256, 0, stream>>>(sum_a, ssq_a, ga, ba, scA, shA, invN);
  bn_relu_ip_k<<<(total8 + 255) / 256, 256, 0, stream>>>(x1, scA, shA, total8);

  // --- shortcut: x @ W1 -> d_out (f32) ---
  sc_gemm_k<<<gsc, 256, 0, stream>>>(x, Bt1, (float*)d_out, N, C1);
  colstats_f32_k<<<512, 256, 0, stream>>>((const float*)d_out, N, sum_s, ssq_s);
  bn_params_k<<<1, 256, 0, stream>>>(sum_s, ssq_s, g1, b1, scS, shS, invN);

  // --- conv_b: fused-v4 from x1 -> convb (pre-BN bf16) ---
  agg_gemm4_k<256, bf16><<<g2, 256, 0, stream>>>(x1, Bt8B, off_p, pcol, inv_p, convb, N);
  colstats_bf16_k<<<512, 256, 0, stream>>>(convb, N, sum_b, ssq_b);
  bn_params_k<<<1, 256, 0, stream>>>(sum_b, ssq_b, gb, bb, scB, shB, invN);

  // --- out = relu(bn(convb) + bn(scp)) ---
  final_out_k<<<(total4 + 255) / 256, 256, 0, stream>>>(
      convb, scB, shB, scS, shS, (float*)d_out, total4);
}

// Round 3
// 891.499 us; speedup vs baseline: 2.8369x; 1.5118x over previous
//
#include <hip/hip_runtime.h>
#include <cstdint>
#include <cstddef>

// GraphResBlock2 on MI355X — round 7: round-6 structure (B direct from L2,
// 2 barriers/section, 17.4 KB LDS) with the spill fixed: __launch_bounds__(256,3).
// Round-6 post-mortem: (256,4) capped VGPR+AGPR at 128/wave -> s[32] spilled to
// scratch -> 1.4 GB of HBM RMW traffic (VGPR_Count 64, WRITE_SIZE 1.06 GB).
// At (256,3) the cap is ~170: acc (64 AGPR) + s[32] + B frags fit.
// N=100000, E=700000, C1=128, C2=256, 7 edge types.

#define N_ET 7

typedef __bf16 bf16;
typedef __bf16 bf16x8 __attribute__((ext_vector_type(8)));
typedef __bf16 bf16x4 __attribute__((ext_vector_type(4)));
typedef float f32x4v __attribute__((ext_vector_type(4)));

// ---------------- CSR build (row-major: seg = row*7 + et) --------

__global__ void count_edges_k(const int* __restrict__ row, const int* __restrict__ et,
                              int* __restrict__ cnt, int E) {
  int e = blockIdx.x * 256 + threadIdx.x;
  if (e < E) atomicAdd(&cnt[row[e] * N_ET + et[e]], 1);
}

__global__ void inv_counts_k(const int* __restrict__ cnt, float* __restrict__ inv, int n) {
  int i = blockIdx.x * 256 + threadIdx.x;
  if (i < n) inv[i] = 1.0f / fmaxf((float)cnt[i], 1.0f);
}

__global__ __launch_bounds__(1024) void scan1_k(const int* __restrict__ cnt,
                                                int* __restrict__ off,
                                                int* __restrict__ bsum, int n) {
  __shared__ int s[1024];
  int tid = threadIdx.x;
  int i = blockIdx.x * 1024 + tid;
  int v = (i < n) ? cnt[i] : 0;
  s[tid] = v;
  __syncthreads();
  for (int d = 1; d < 1024; d <<= 1) {
    int t = (tid >= d) ? s[tid - d] : 0;
    __syncthreads();
    s[tid] += t;
    __syncthreads();
  }
  if (i < n) off[i] = s[tid] - v;
  if (tid == 1023) bsum[blockIdx.x] = s[1023];
}

__global__ __launch_bounds__(1024) void scan2_k(int* __restrict__ bsum, int nb) {
  __shared__ int s[1024];
  int tid = threadIdx.x;
  int v = (tid < nb) ? bsum[tid] : 0;
  s[tid] = v;
  __syncthreads();
  for (int d = 1; d < 1024; d <<= 1) {
    int t = (tid >= d) ? s[tid - d] : 0;
    __syncthreads();
    s[tid] += t;
    __syncthreads();
  }
  if (tid < nb) bsum[tid] = s[tid] - v;
}

__global__ __launch_bounds__(1024) void scan3_k(int* __restrict__ off,
                                                const int* __restrict__ bsum,
                                                int n, int total) {
  int i = blockIdx.x * 1024 + threadIdx.x;
  if (i < n) off[i] += bsum[blockIdx.x];
  if (i == 0) off[n] = total;
}

__global__ void place_k(const int* __restrict__ row, const int* __restrict__ col,
                        const int* __restrict__ et, const int* __restrict__ off,
                        int* __restrict__ cur, int* __restrict__ pcol, int E) {
  int e = blockIdx.x * 256 + threadIdx.x;
  if (e >= E) return;
  int seg = row[e] * N_ET + et[e];
  int pos = off[seg] + atomicAdd(&cur[seg], 1);
  pcol[pos] = col[e];
}

// ---------------- weight transposes ----------------
// panel layout: Bt8[k>>3][col][k&7]  (16B per (k-panel, col))
__global__ void transpose_w8_k(const float* __restrict__ W, bf16* __restrict__ Bt8, int K) {
  int i = blockIdx.x * 256 + threadIdx.x;
  if (i < K * 256) {
    int k = i >> 8, col = i & 255;
    Bt8[((size_t)(k >> 3) * 256 + col) * 8 + (k & 7)] = (bf16)W[i];
  }
}

// old layout for the shortcut kernel: Bt[col][k]
__global__ void transpose_w_k(const float* __restrict__ W, bf16* __restrict__ Bt, int K) {
  int i = blockIdx.x * 256 + threadIdx.x;
  if (i < K * 256) {
    int k = i >> 8, n = i & 255;
    Bt[(size_t)n * K + k] = (bf16)W[i];
  }
}

// ---------------- fused-v5: section-hoisted aggregate + GEMM, B from L2 ------
// Cout[M,256] (bf16) = Aeff[M, 7*CW] @ W, where
//   Aeff[m, type*CW + c] = inv[m*7+type] * sum_{p in seg(m,type)} X[pcol[p], c]
// Tile: 64 rows x 256 cols, 4 waves (2x2 -> 32 rows x 128 cols each).
// K processed in 128-wide sections; aggregation hoisted once per section
// (thread (r = t>>2, h = t&3) aggregates 32 channels of row r).
// B fragments read DIRECTLY from L2-resident Bt8 per MFMA (no Bs staging,
// no per-kk barriers): 2 barriers per section total.
// __launch_bounds__(256,3): VGPR+AGPR cap ~170 -> NO SPILL (round-6 lesson).
template <int CW, typename XT>
__launch_bounds__(256, 3)
__global__ void agg_gemm5_k(const XT* __restrict__ X, const bf16* __restrict__ Bt8,
                            const int* __restrict__ off, const int* __restrict__ pcol,
                            const float* __restrict__ inv, bf16* __restrict__ Cout,
                            int M) {
  __shared__ alignas(16) bf16 As[64][136];          // 64 rows x 128-col section (+8 pad)

  const int t = threadIdx.x;
  const int m0 = blockIdx.x * 64;
  const int lane = t & 63, w = t >> 6;
  const int wm = (w >> 1) * 32;
  const int wn = (w & 1) * 128;
  const int l15 = lane & 15, quad = lane >> 4;

  const int r = t >> 2, h = t & 3;                  // agg mapping
  const int m = m0 + r;
  const bool mv = (m < M);

  f32x4v acc[2][8];
#pragma unroll
  for (int i = 0; i < 2; ++i)
#pragma unroll
    for (int j = 0; j < 8; ++j) acc[i][j] = (f32x4v){0.f, 0.f, 0.f, 0.f};

  const int NSEC = (N_ET * CW) / 128;

  for (int sec = 0; sec < NSEC; ++sec) {
    // ---- aggregate this thread's (row, 32-channel) slice of the section ----
    const int type = (CW == 128) ? sec : (sec >> 1);
    const int xcol = ((sec * 128) & (CW - 1)) + h * 32;  // column base in X
    int sS = 0, sE = 0;
    float sc = 0.f;
    if (mv) {
      int seg = m * N_ET + type;
      sS = off[seg];
      sE = off[seg + 1];
      sc = inv[seg];
    }
    float s[32];
#pragma unroll
    for (int j = 0; j < 32; ++j) s[j] = 0.f;
    // prefetch next pcol to overlap index load with X row loads
    int p = sS;
    int nc = (p < sE) ? pcol[p] : 0;
    while (p < sE) {
      const int cI = nc;
      if (p + 1 < sE) nc = pcol[p + 1];
      if constexpr (sizeof(XT) == 4) {
        const float* xp = (const float*)X + (size_t)cI * CW + xcol;
#pragma unroll
        for (int j = 0; j < 8; ++j) {
          float4 v = *(const float4*)(xp + j * 4);
          s[j * 4 + 0] += v.x; s[j * 4 + 1] += v.y;
          s[j * 4 + 2] += v.z; s[j * 4 + 3] += v.w;
        }
      } else {
        const bf16* xp = (const bf16*)X + (size_t)cI * CW + xcol;
#pragma unroll
        for (int j = 0; j < 4; ++j) {
          bf16x8 v = *(const bf16x8*)(xp + j * 8);
#pragma unroll
          for (int i = 0; i < 8; ++i) s[j * 8 + i] += (float)v[i];
        }
      }
      ++p;
    }
    __syncthreads();   // (b1) all waves done reading previous As
#pragma unroll
    for (int j = 0; j < 4; ++j) {
      bf16x8 o;
#pragma unroll
      for (int i = 0; i < 8; ++i) o[i] = (bf16)(s[j * 8 + i] * sc);
      *(bf16x8*)&As[r][h * 32 + j * 8] = o;
    }
    __syncthreads();   // (b2) As visible to all waves

    // ---- 4 k-iters over this section; B frags straight from L2 ----
#pragma unroll
    for (int kk = 0; kk < 4; ++kk) {
      const int k8b = sec * 16 + kk * 4;
      const bf16* bp = Bt8 + (size_t)(k8b + quad) * (256 * 8);
      bf16x8 bfr[8];
#pragma unroll
      for (int g = 0; g < 8; ++g)
        bfr[g] = *(const bf16x8*)(bp + (size_t)(wn + g * 16 + l15) * 8);
      bf16x8 af[2];
#pragma unroll
      for (int f = 0; f < 2; ++f)
        af[f] = *(const bf16x8*)&As[wm + f * 16 + l15][kk * 32 + quad * 8];
#pragma unroll
      for (int fi = 0; fi < 2; ++fi)
#pragma unroll
        for (int fj = 0; fj < 8; ++fj)
          acc[fi][fj] = __builtin_amdgcn_mfma_f32_16x16x32_bf16(af[fi], bfr[fj], acc[fi][fj], 0, 0, 0);
    }
  }

  // ---- epilogue: bf16 store ----
#pragma unroll
  for (int fi = 0; fi < 2; ++fi) {
    int rbase = m0 + wm + fi * 16 + quad * 4;
#pragma unroll
    for (int rr = 0; rr < 4; ++rr) {
      int rowg = rbase + rr;
      if (rowg < M) {
#pragma unroll
        for (int fj = 0; fj < 8; ++fj)
          Cout[(size_t)rowg * 256 + wn + fj * 16 + l15] = (bf16)acc[fi][fj][rr];
      }
    }
  }
}

// ---------------- shortcut dense GEMM (proven, unchanged) ----------------
__launch_bounds__(256, 2)
__global__ void sc_gemm_k(const float* __restrict__ X, const bf16* __restrict__ Bt,
                          float* __restrict__ Cout, int M, int K) {
  __shared__ alignas(16) bf16 As[128][40];
  __shared__ alignas(16) bf16 Bs[256][40];
  const int t = threadIdx.x;
  const int m0 = blockIdx.x * 128;
  const int lane = t & 63, w = t >> 6;
  const int wm = (w >> 1) * 64;
  const int wn = (w & 1) * 128;
  const int l15 = lane & 15, quad = lane >> 4;

  f32x4v acc[4][8];
#pragma unroll
  for (int i = 0; i < 4; ++i)
#pragma unroll
    for (int j = 0; j < 8; ++j) acc[i][j] = (f32x4v){0.f, 0.f, 0.f, 0.f};

  const int r = t >> 1, h = t & 1;
  const int m = m0 + r;
  const bool mv = (m < M);

  for (int k0 = 0; k0 < K; k0 += 32) {
    const float* xp = X + (size_t)m * K + k0 + h * 16;
    float4 v0, v1, v2, v3;
    if (mv) {
      v0 = *(const float4*)(xp + 0);
      v1 = *(const float4*)(xp + 4);
      v2 = *(const float4*)(xp + 8);
      v3 = *(const float4*)(xp + 12);
    } else {
      v0 = v1 = v2 = v3 = make_float4(0.f, 0.f, 0.f, 0.f);
    }
    bf16x8 o0, o1;
    o0[0] = (bf16)v0.x; o0[1] = (bf16)v0.y; o0[2] = (bf16)v0.z; o0[3] = (bf16)v0.w;
    o0[4] = (bf16)v1.x; o0[5] = (bf16)v1.y; o0[6] = (bf16)v1.z; o0[7] = (bf16)v1.w;
    o1[0] = (bf16)v2.x; o1[1] = (bf16)v2.y; o1[2] = (bf16)v2.z; o1[3] = (bf16)v2.w;
    o1[4] = (bf16)v3.x; o1[5] = (bf16)v3.y; o1[6] = (bf16)v3.z; o1[7] = (bf16)v3.w;
    *(bf16x8*)&As[r][h * 16] = o0;
    *(bf16x8*)&As[r][h * 16 + 8] = o1;
    {
      const bf16* bp = Bt + (size_t)t * K + k0;
      bf16x8 b0 = *(const bf16x8*)(bp + 0);
      bf16x8 b1 = *(const bf16x8*)(bp + 8);
      bf16x8 b2 = *(const bf16x8*)(bp + 16);
      bf16x8 b3 = *(const bf16x8*)(bp + 24);
      *(bf16x8*)&Bs[t][0] = b0;
      *(bf16x8*)&Bs[t][8] = b1;
      *(bf16x8*)&Bs[t][16] = b2;
      *(bf16x8*)&Bs[t][24] = b3;
    }
    __syncthreads();
    bf16x8 af[4], bfr[8];
#pragma unroll
    for (int f = 0; f < 4; ++f) af[f] = *(const bf16x8*)&As[wm + f * 16 + l15][quad * 8];
#pragma unroll
    for (int g = 0; g < 8; ++g) bfr[g] = *(const bf16x8*)&Bs[wn + g * 16 + l15][quad * 8];
#pragma unroll
    for (int fi = 0; fi < 4; ++fi)
#pragma unroll
      for (int fj = 0; fj < 8; ++fj)
        acc[fi][fj] = __builtin_amdgcn_mfma_f32_16x16x32_bf16(af[fi], bfr[fj], acc[fi][fj], 0, 0, 0);
    __syncthreads();
  }

#pragma unroll
  for (int fi = 0; fi < 4; ++fi) {
    int rbase = m0 + wm + fi * 16 + quad * 4;
#pragma unroll
    for (int rr = 0; rr < 4; ++rr) {
      int rowg = rbase + rr;
      if (rowg < M) {
#pragma unroll
        for (int fj = 0; fj < 8; ++fj)
          Cout[(size_t)rowg * 256 + wn + fj * 16 + l15] = acc[fi][fj][rr];
      }
    }
  }
}

// ---------------- BN stats / params / elementwise ----------------

__global__ void colstats_bf16_k(const bf16* __restrict__ v, int N,
                                float* __restrict__ s, float* __restrict__ q) {
  int c = threadIdx.x;
  float a = 0.f, b = 0.f;
  for (int r = blockIdx.x; r < N; r += gridDim.x) {
    float x = (float)v[(size_t)r * 256 + c];
    a += x;
    b += x * x;
  }
  unsafeAtomicAdd(&s[c], a);
  unsafeAtomicAdd(&q[c], b);
}

__global__ void colstats_f32_k(const float* __restrict__ v, int N,
                               float* __restrict__ s, float* __restrict__ q) {
  int c = threadIdx.x;
  float a = 0.f, b = 0.f;
  for (int r = blockIdx.x; r < N; r += gridDim.x) {
    float x = v[(size_t)r * 256 + c];
    a += x;
    b += x * x;
  }
  unsafeAtomicAdd(&s[c], a);
  unsafeAtomicAdd(&q[c], b);
}

__global__ void bn_params_k(const float* __restrict__ s, const float* __restrict__ q,
                            const float* __restrict__ g, const float* __restrict__ b,
                            float* __restrict__ scale, float* __restrict__ shift, float invN) {
  int c = threadIdx.x;
  float m = s[c] * invN;
  float var = fmaxf(q[c] * invN - m * m, 0.f);
  float sc = g[c] * rsqrtf(var + 1e-5f);
  scale[c] = sc;
  shift[c] = b[c] - m * sc;
}

__global__ void bn_relu_ip_k(bf16* __restrict__ v, const float* __restrict__ scale,
                             const float* __restrict__ shift, int total8) {
  int i = blockIdx.x * 256 + threadIdx.x;
  if (i >= total8) return;
  size_t base = (size_t)i * 8;
  int c = (int)(base & 255);
  bf16x8 x = *(const bf16x8*)(v + base);
#pragma unroll
  for (int j = 0; j < 8; ++j)
    x[j] = (bf16)fmaxf((float)x[j] * scale[c + j] + shift[c + j], 0.f);
  *(bf16x8*)(v + base) = x;
}

__global__ void final_out_k(const bf16* __restrict__ cb,
                            const float* __restrict__ scB, const float* __restrict__ shB,
                            const float* __restrict__ scS, const float* __restrict__ shS,
                            float* __restrict__ out, int total4) {
  int i = blockIdx.x * 256 + threadIdx.x;
  if (i >= total4) return;
  size_t base = (size_t)i * 4;
  int c = (int)(base & 255);
  bf16x4 vb = *(const bf16x4*)(cb + base);
  float4 vs = *(const float4*)(out + base);
  float4 r;
  r.x = fmaxf((float)vb[0] * scB[c + 0] + shB[c + 0] + vs.x * scS[c + 0] + shS[c + 0], 0.f);
  r.y = fmaxf((float)vb[1] * scB[c + 1] + shB[c + 1] + vs.y * scS[c + 1] + shS[c + 1], 0.f);
  r.z = fmaxf((float)vb[2] * scB[c + 2] + shB[c + 2] + vs.z * scS[c + 2] + shS[c + 2], 0.f);
  r.w = fmaxf((float)vb[3] * scB[c + 3] + shB[c + 3] + vs.w * scS[c + 3] + shS[c + 3], 0.f);
  *(float4*)(out + base) = r;
}

__global__ void sentinel_k(float* __restrict__ out, int n) {
  int i = blockIdx.x * 256 + threadIdx.x;
  if (i < n) out[i] = 12345.0f;
}

// ---------------- launch ----------------

extern "C" void kernel_launch(void* const* d_in, const int* in_sizes, int n_in,
                              void* d_out, int out_size, void* d_ws, size_t ws_size,
                              hipStream_t stream) {
  const float* x  = (const float*)d_in[0];
  const int* ei   = (const int*)d_in[1];
  const int* etp  = (const int*)d_in[2];
  const float* Wa = (const float*)d_in[4];
  const float* ga = (const float*)d_in[5];
  const float* ba = (const float*)d_in[6];
  const float* Wb = (const float*)d_in[7];
  const float* gb = (const float*)d_in[8];
  const float* bb = (const float*)d_in[9];
  const float* W1 = (const float*)d_in[10];
  const float* g1 = (const float*)d_in[11];
  const float* b1 = (const float*)d_in[12];

  const int C1 = 128, C2 = 256;
  const int N = in_sizes[0] / C1;   // 100000
  const int E = in_sizes[2];        // 700000
  const int* row = ei;
  const int* col = ei + E;
  const int NS = N * N_ET;
  const int KA = N_ET * C1;         // 896
  const int KB = N_ET * C2;         // 1792

  size_t need = 0;
  auto alloc = [&](size_t bytes) { size_t o = need; need += (bytes + 15) & ~(size_t)15; return o; };
  char* w = (char*)d_ws;
  int*   off_p = (int*)(w + alloc(((size_t)NS + 1) * 4));
  int*   cnt_p = (int*)(w + alloc((size_t)NS * 4));
  int*   pcol  = (int*)(w + alloc((size_t)E * 4));
  float* inv_p = (float*)(w + alloc((size_t)NS * 4));
  int*   bsum  = (int*)(w + alloc(1024 * 4));
  bf16*  Bt8A  = (bf16*)(w + alloc((size_t)KA * 256 * 2));
  bf16*  Bt8B  = (bf16*)(w + alloc((size_t)KB * 256 * 2));
  bf16*  Bt1   = (bf16*)(w + alloc((size_t)256 * C1 * 2));
  bf16*  x1    = (bf16*)(w + alloc((size_t)N * C2 * 2));
  bf16*  convb = (bf16*)(w + alloc((size_t)N * C2 * 2));
  float* st    = (float*)(w + alloc(12 * 256 * 4));

  if (ws_size < need) {
    sentinel_k<<<(out_size + 255) / 256, 256, 0, stream>>>((float*)d_out, out_size);
    return;
  }

  float* sum_a = st + 0 * 256, *ssq_a = st + 1 * 256;
  float* sum_b = st + 2 * 256, *ssq_b = st + 3 * 256;
  float* sum_s = st + 4 * 256, *ssq_s = st + 5 * 256;
  float* scA = st + 6 * 256, *shA = st + 7 * 256;
  float* scB = st + 8 * 256, *shB = st + 9 * 256;
  float* scS = st + 10 * 256, *shS = st + 11 * 256;

  const float invN = 1.0f / (float)N;
  const int nscan = (NS + 1023) / 1024;
  const int g2 = (N + 63) / 64;          // fused grid (64-row tiles)
  const int gsc = (N + 127) / 128;       // shortcut grid
  const int total8 = N * C2 / 8;
  const int total4 = N * C2 / 4;

  // --- CSR build ---
  hipMemsetAsync(cnt_p, 0, (size_t)NS * 4, stream);
  hipMemsetAsync(st, 0, 12 * 256 * 4, stream);
  count_edges_k<<<(E + 255) / 256, 256, 0, stream>>>(row, etp, cnt_p, E);
  inv_counts_k<<<(NS + 255) / 256, 256, 0, stream>>>(cnt_p, inv_p, NS);
  scan1_k<<<nscan, 1024, 0, stream>>>(cnt_p, off_p, bsum, NS);
  scan2_k<<<1, 1024, 0, stream>>>(bsum, nscan);
  scan3_k<<<nscan, 1024, 0, stream>>>(off_p, bsum, NS, E);
  hipMemsetAsync(cnt_p, 0, (size_t)NS * 4, stream);
  place_k<<<(E + 255) / 256, 256, 0, stream>>>(row, col, etp, off_p, cnt_p, pcol, E);

  // --- weight transposes ---
  transpose_w8_k<<<(KA * 256 + 255) / 256, 256, 0, stream>>>(Wa, Bt8A, KA);
  transpose_w8_k<<<(KB * 256 + 255) / 256, 256, 0, stream>>>(Wb, Bt8B, KB);
  transpose_w_k<<<(C1 * 256 + 255) / 256, 256, 0, stream>>>(W1, Bt1, C1);

  // --- conv_a: fused-v5 -> x1 (pre-BN bf16), then BN+ReLU in place ---
  agg_gemm5_k<128, float><<<g2, 256, 0, stream>>>(x, Bt8A, off_p, pcol, inv_p, x1, N);
  colstats_bf16_k<<<512, 256, 0, stream>>>(x1, N, sum_a, ssq_a);
  bn_params_k<<<1, 256, 0, stream>>>(sum_a, ssq_a, ga, ba, scA, shA, invN);
  bn_relu_ip_k<<<(total8 + 255) / 256, 256, 0, stream>>>(x1, scA, shA, total8);

  // --- shortcut: x @ W1 -> d_out (f32) ---
  sc_gemm_k<<<gsc, 256, 0, stream>>>(x, Bt1, (float*)d_out, N, C1);
  colstats_f32_k<<<512, 256, 0, stream>>>((const float*)d_out, N, sum_s, ssq_s);
  bn_params_k<<<1, 256, 0, stream>>>(sum_s, ssq_s, g1, b1, scS, shS, invN);

  // --- conv_b: fused-v5 from x1 -> convb (pre-BN bf16) ---
  agg_gemm5_k<256, bf16><<<g2, 256, 0, stream>>>(x1, Bt8B, off_p, pcol, inv_p, convb, N);
  colstats_bf16_k<<<512, 256, 0, stream>>>(convb, N, sum_b, ssq_b);
  bn_params_k<<<1, 256, 0, stream>>>(sum_b, ssq_b, gb, bb, scB, shB, invN);

  // --- out = relu(bn(convb) + bn(scp)) ---
  final_out_k<<<(total4 + 255) / 256, 256, 0, stream>>>(
      convb, scB, shB, scS, shS, (float*)d_out, total4);
}

// Round 4
// 888.601 us; speedup vs baseline: 2.8461x; 1.0033x over previous
//
#include <hip/hip_runtime.h>
#include <cstdint>
#include <cstddef>

// GraphResBlock2 on MI355X — round 8: occupancy doubling via thin waves.
// Round-7 post-mortem: 84 VGPR + 64 AGPR = 148 regs -> 8 waves/CU (m69 halving
// rule), latency-bound on random X gathers (MfmaUtil 16%, stall ~70% of time).
// This round: 512-thread blocks (8 waves, 2x4 wave grid) on the same 64x256
// tile -> acc 32 AGPR + s[16] -> total ~96 regs <= 128 -> 16 waves/CU.
// off/inv hoisted to LDS once per tile (kills per-section off-chain latency).
// B stays direct-from-L2 (wave grid chosen so B L2 traffic is NOT duplicated).
// N=100000, E=700000, C1=128, C2=256, 7 edge types.

#define N_ET 7

typedef __bf16 bf16;
typedef __bf16 bf16x8 __attribute__((ext_vector_type(8)));
typedef __bf16 bf16x4 __attribute__((ext_vector_type(4)));
typedef float f32x4v __attribute__((ext_vector_type(4)));

// ---------------- CSR build (row-major: seg = row*7 + et) --------

__global__ void count_edges_k(const int* __restrict__ row, const int* __restrict__ et,
                              int* __restrict__ cnt, int E) {
  int e = blockIdx.x * 256 + threadIdx.x;
  if (e < E) atomicAdd(&cnt[row[e] * N_ET + et[e]], 1);
}

__global__ void inv_counts_k(const int* __restrict__ cnt, float* __restrict__ inv, int n) {
  int i = blockIdx.x * 256 + threadIdx.x;
  if (i < n) inv[i] = 1.0f / fmaxf((float)cnt[i], 1.0f);
}

__global__ __launch_bounds__(1024) void scan1_k(const int* __restrict__ cnt,
                                                int* __restrict__ off,
                                                int* __restrict__ bsum, int n) {
  __shared__ int s[1024];
  int tid = threadIdx.x;
  int i = blockIdx.x * 1024 + tid;
  int v = (i < n) ? cnt[i] : 0;
  s[tid] = v;
  __syncthreads();
  for (int d = 1; d < 1024; d <<= 1) {
    int t = (tid >= d) ? s[tid - d] : 0;
    __syncthreads();
    s[tid] += t;
    __syncthreads();
  }
  if (i < n) off[i] = s[tid] - v;
  if (tid == 1023) bsum[blockIdx.x] = s[1023];
}

__global__ __launch_bounds__(1024) void scan2_k(int* __restrict__ bsum, int nb) {
  __shared__ int s[1024];
  int tid = threadIdx.x;
  int v = (tid < nb) ? bsum[tid] : 0;
  s[tid] = v;
  __syncthreads();
  for (int d = 1; d < 1024; d <<= 1) {
    int t = (tid >= d) ? s[tid - d] : 0;
    __syncthreads();
    s[tid] += t;
    __syncthreads();
  }
  if (tid < nb) bsum[tid] = s[tid] - v;
}

__global__ __launch_bounds__(1024) void scan3_k(int* __restrict__ off,
                                                const int* __restrict__ bsum,
                                                int n, int total) {
  int i = blockIdx.x * 1024 + threadIdx.x;
  if (i < n) off[i] += bsum[blockIdx.x];
  if (i == 0) off[n] = total;
}

__global__ void place_k(const int* __restrict__ row, const int* __restrict__ col,
                        const int* __restrict__ et, const int* __restrict__ off,
                        int* __restrict__ cur, int* __restrict__ pcol, int E) {
  int e = blockIdx.x * 256 + threadIdx.x;
  if (e >= E) return;
  int seg = row[e] * N_ET + et[e];
  int pos = off[seg] + atomicAdd(&cur[seg], 1);
  pcol[pos] = col[e];
}

// ---------------- weight transposes ----------------
// panel layout: Bt8[k>>3][col][k&7]  (16B per (k-panel, col))
__global__ void transpose_w8_k(const float* __restrict__ W, bf16* __restrict__ Bt8, int K) {
  int i = blockIdx.x * 256 + threadIdx.x;
  if (i < K * 256) {
    int k = i >> 8, col = i & 255;
    Bt8[((size_t)(k >> 3) * 256 + col) * 8 + (k & 7)] = (bf16)W[i];
  }
}

// old layout for the shortcut kernel: Bt[col][k]
__global__ void transpose_w_k(const float* __restrict__ W, bf16* __restrict__ Bt, int K) {
  int i = blockIdx.x * 256 + threadIdx.x;
  if (i < K * 256) {
    int k = i >> 8, n = i & 255;
    Bt[(size_t)n * K + k] = (bf16)W[i];
  }
}

// ---------------- fused-v6: thin-wave aggregate + GEMM, B from L2 ------------
// Cout[M,256] (bf16) = Aeff[M, 7*CW] @ W, where
//   Aeff[m, type*CW + c] = inv[m*7+type] * sum_{p in seg(m,type)} X[pcol[p], c]
// Tile: 64 rows x 256 cols, 8 waves (2x4 -> 32 rows x 64 cols each).
// Aggregation: thread (r = t>>3, h = t&7) aggregates 16 channels of row r.
// off/inv for the tile staged in LDS once (no per-section global off chain).
// B fragments direct from L2-resident Bt8. 2 barriers per section.
// __launch_bounds__(512,4): cap 128 regs -> 16 waves/CU (2 blocks).
template <int CW, typename XT>
__launch_bounds__(512, 4)
__global__ void agg_gemm6_k(const XT* __restrict__ X, const bf16* __restrict__ Bt8,
                            const int* __restrict__ off, const int* __restrict__ pcol,
                            const float* __restrict__ inv, bf16* __restrict__ Cout,
                            int M) {
  __shared__ alignas(16) bf16 As[64][136];   // 64 rows x 128-col section (+8 pad)
  __shared__ int   offL[64 * N_ET + 1];      // tile's off window
  __shared__ float invL[64 * N_ET];          // tile's inv window

  const int t = threadIdx.x;
  const int m0 = blockIdx.x * 64;
  const int lane = t & 63, w = t >> 6;       // 8 waves
  const int wm = (w >> 2) * 32;              // 2 row-groups of 32
  const int wn = (w & 3) * 64;               // 4 col-groups of 64
  const int l15 = lane & 15, quad = lane >> 4;

  const int r = t >> 3, h = t & 7;           // agg: 64 rows x 8 slices x 16 ch
  const int NS_ = M * N_ET;

  // ---- stage off/inv window for this tile into LDS (one coalesced pass) ----
  {
    const int base = m0 * N_ET;
    for (int i = t; i < 64 * N_ET + 1; i += 512) {
      int gi = base + i;
      if (gi > NS_) gi = NS_;
      offL[i] = off[gi];
    }
    for (int i = t; i < 64 * N_ET; i += 512) {
      int gi = base + i;
      if (gi >= NS_) gi = NS_ - 1;
      invL[i] = inv[gi];
    }
  }

  f32x4v acc[2][4];
#pragma unroll
  for (int i = 0; i < 2; ++i)
#pragma unroll
    for (int j = 0; j < 4; ++j) acc[i][j] = (f32x4v){0.f, 0.f, 0.f, 0.f};

  const int NSEC = (N_ET * CW) / 128;
  __syncthreads();                           // offL/invL visible

  for (int sec = 0; sec < NSEC; ++sec) {
    const int type = (CW == 128) ? sec : (sec >> 1);
    const int xcol = ((sec * 128) & (CW - 1)) + h * 16;   // column base in X
    const int ls = r * N_ET + type;
    const int sS = offL[ls];
    const int sE = offL[ls + 1];
    const float sc = invL[ls];

    float s[16];
#pragma unroll
    for (int j = 0; j < 16; ++j) s[j] = 0.f;

    // walk the segment; pcol window for the tile is ~1.8 KB contiguous -> L1-hot
    int p = sS;
    int nc = (p < sE) ? pcol[p] : 0;
    while (p < sE) {
      const int cI = nc;
      if (p + 1 < sE) nc = pcol[p + 1];
      if constexpr (sizeof(XT) == 4) {
        const float* xp = (const float*)X + (size_t)cI * CW + xcol;
#pragma unroll
        for (int j = 0; j < 4; ++j) {
          float4 v = *(const float4*)(xp + j * 4);
          s[j * 4 + 0] += v.x; s[j * 4 + 1] += v.y;
          s[j * 4 + 2] += v.z; s[j * 4 + 3] += v.w;
        }
      } else {
        const bf16* xp = (const bf16*)X + (size_t)cI * CW + xcol;
        bf16x8 v0 = *(const bf16x8*)(xp);
        bf16x8 v1 = *(const bf16x8*)(xp + 8);
#pragma unroll
        for (int i = 0; i < 8; ++i) {
          s[i] += (float)v0[i];
          s[8 + i] += (float)v1[i];
        }
      }
      ++p;
    }
    __syncthreads();   // (b1) all waves done reading previous As
    {
      bf16x8 o0, o1;
#pragma unroll
      for (int i = 0; i < 8; ++i) {
        o0[i] = (bf16)(s[i] * sc);
        o1[i] = (bf16)(s[8 + i] * sc);
      }
      *(bf16x8*)&As[r][h * 16] = o0;
      *(bf16x8*)&As[r][h * 16 + 8] = o1;
    }
    __syncthreads();   // (b2) As visible to all waves

    // ---- 4 k-iters over this section; B frags straight from L2 ----
#pragma unroll
    for (int kk = 0; kk < 4; ++kk) {
      const int k8b = sec * 16 + kk * 4;
      const bf16* bp = Bt8 + (size_t)(k8b + quad) * (256 * 8);
      bf16x8 bfr[4];
#pragma unroll
      for (int g = 0; g < 4; ++g)
        bfr[g] = *(const bf16x8*)(bp + (size_t)(wn + g * 16 + l15) * 8);
      bf16x8 af[2];
#pragma unroll
      for (int f = 0; f < 2; ++f)
        af[f] = *(const bf16x8*)&As[wm + f * 16 + l15][kk * 32 + quad * 8];
#pragma unroll
      for (int fi = 0; fi < 2; ++fi)
#pragma unroll
        for (int fj = 0; fj < 4; ++fj)
          acc[fi][fj] = __builtin_amdgcn_mfma_f32_16x16x32_bf16(af[fi], bfr[fj], acc[fi][fj], 0, 0, 0);
    }
  }

  // ---- epilogue: bf16 store ----
#pragma unroll
  for (int fi = 0; fi < 2; ++fi) {
    int rbase = m0 + wm + fi * 16 + quad * 4;
#pragma unroll
    for (int rr = 0; rr < 4; ++rr) {
      int rowg = rbase + rr;
      if (rowg < M) {
#pragma unroll
        for (int fj = 0; fj < 4; ++fj)
          Cout[(size_t)rowg * 256 + wn + fj * 16 + l15] = (bf16)acc[fi][fj][rr];
      }
    }
  }
}

// ---------------- shortcut dense GEMM (proven, unchanged) ----------------
__launch_bounds__(256, 2)
__global__ void sc_gemm_k(const float* __restrict__ X, const bf16* __restrict__ Bt,
                          float* __restrict__ Cout, int M, int K) {
  __shared__ alignas(16) bf16 As[128][40];
  __shared__ alignas(16) bf16 Bs[256][40];
  const int t = threadIdx.x;
  const int m0 = blockIdx.x * 128;
  const int lane = t & 63, w = t >> 6;
  const int wm = (w >> 1) * 64;
  const int wn = (w & 1) * 128;
  const int l15 = lane & 15, quad = lane >> 4;

  f32x4v acc[4][8];
#pragma unroll
  for (int i = 0; i < 4; ++i)
#pragma unroll
    for (int j = 0; j < 8; ++j) acc[i][j] = (f32x4v){0.f, 0.f, 0.f, 0.f};

  const int r = t >> 1, h = t & 1;
  const int m = m0 + r;
  const bool mv = (m < M);

  for (int k0 = 0; k0 < K; k0 += 32) {
    const float* xp = X + (size_t)m * K + k0 + h * 16;
    float4 v0, v1, v2, v3;
    if (mv) {
      v0 = *(const float4*)(xp + 0);
      v1 = *(const float4*)(xp + 4);
      v2 = *(const float4*)(xp + 8);
      v3 = *(const float4*)(xp + 12);
    } else {
      v0 = v1 = v2 = v3 = make_float4(0.f, 0.f, 0.f, 0.f);
    }
    bf16x8 o0, o1;
    o0[0] = (bf16)v0.x; o0[1] = (bf16)v0.y; o0[2] = (bf16)v0.z; o0[3] = (bf16)v0.w;
    o0[4] = (bf16)v1.x; o0[5] = (bf16)v1.y; o0[6] = (bf16)v1.z; o0[7] = (bf16)v1.w;
    o1[0] = (bf16)v2.x; o1[1] = (bf16)v2.y; o1[2] = (bf16)v2.z; o1[3] = (bf16)v2.w;
    o1[4] = (bf16)v3.x; o1[5] = (bf16)v3.y; o1[6] = (bf16)v3.z; o1[7] = (bf16)v3.w;
    *(bf16x8*)&As[r][h * 16] = o0;
    *(bf16x8*)&As[r][h * 16 + 8] = o1;
    {
      const bf16* bp = Bt + (size_t)t * K + k0;
      bf16x8 b0 = *(const bf16x8*)(bp + 0);
      bf16x8 b1 = *(const bf16x8*)(bp + 8);
      bf16x8 b2 = *(const bf16x8*)(bp + 16);
      bf16x8 b3 = *(const bf16x8*)(bp + 24);
      *(bf16x8*)&Bs[t][0] = b0;
      *(bf16x8*)&Bs[t][8] = b1;
      *(bf16x8*)&Bs[t][16] = b2;
      *(bf16x8*)&Bs[t][24] = b3;
    }
    __syncthreads();
    bf16x8 af[4], bfr[8];
#pragma unroll
    for (int f = 0; f < 4; ++f) af[f] = *(const bf16x8*)&As[wm + f * 16 + l15][quad * 8];
#pragma unroll
    for (int g = 0; g < 8; ++g) bfr[g] = *(const bf16x8*)&Bs[wn + g * 16 + l15][quad * 8];
#pragma unroll
    for (int fi = 0; fi < 4; ++fi)
#pragma unroll
      for (int fj = 0; fj < 8; ++fj)
        acc[fi][fj] = __builtin_amdgcn_mfma_f32_16x16x32_bf16(af[fi], bfr[fj], acc[fi][fj], 0, 0, 0);
    __syncthreads();
  }

#pragma unroll
  for (int fi = 0; fi < 4; ++fi) {
    int rbase = m0 + wm + fi * 16 + quad * 4;
#pragma unroll
    for (int rr = 0; rr < 4; ++rr) {
      int rowg = rbase + rr;
      if (rowg < M) {
#pragma unroll
        for (int fj = 0; fj < 8; ++fj)
          Cout[(size_t)rowg * 256 + wn + fj * 16 + l15] = acc[fi][fj][rr];
      }
    }
  }
}

// ---------------- BN stats / params / elementwise ----------------

__global__ void colstats_bf16_k(const bf16* __restrict__ v, int N,
                                float* __restrict__ s, float* __restrict__ q) {
  int c = threadIdx.x;
  float a = 0.f, b = 0.f;
  for (int r = blockIdx.x; r < N; r += gridDim.x) {
    float x = (float)v[(size_t)r * 256 + c];
    a += x;
    b += x * x;
  }
  unsafeAtomicAdd(&s[c], a);
  unsafeAtomicAdd(&q[c], b);
}

__global__ void colstats_f32_k(const float* __restrict__ v, int N,
                               float* __restrict__ s, float* __restrict__ q) {
  int c = threadIdx.x;
  float a = 0.f, b = 0.f;
  for (int r = blockIdx.x; r < N; r += gridDim.x) {
    float x = v[(size_t)r * 256 + c];
    a += x;
    b += x * x;
  }
  unsafeAtomicAdd(&s[c], a);
  unsafeAtomicAdd(&q[c], b);
}

__global__ void bn_params_k(const float* __restrict__ s, const float* __restrict__ q,
                            const float* __restrict__ g, const float* __restrict__ b,
                            float* __restrict__ scale, float* __restrict__ shift, float invN) {
  int c = threadIdx.x;
  float m = s[c] * invN;
  float var = fmaxf(q[c] * invN - m * m, 0.f);
  float sc = g[c] * rsqrtf(var + 1e-5f);
  scale[c] = sc;
  shift[c] = b[c] - m * sc;
}

__global__ void bn_relu_ip_k(bf16* __restrict__ v, const float* __restrict__ scale,
                             const float* __restrict__ shift, int total8) {
  int i = blockIdx.x * 256 + threadIdx.x;
  if (i >= total8) return;
  size_t base = (size_t)i * 8;
  int c = (int)(base & 255);
  bf16x8 x = *(const bf16x8*)(v + base);
#pragma unroll
  for (int j = 0; j < 8; ++j)
    x[j] = (bf16)fmaxf((float)x[j] * scale[c + j] + shift[c + j], 0.f);
  *(bf16x8*)(v + base) = x;
}

__global__ void final_out_k(const bf16* __restrict__ cb,
                            const float* __restrict__ scB, const float* __restrict__ shB,
                            const float* __restrict__ scS, const float* __restrict__ shS,
                            float* __restrict__ out, int total4) {
  int i = blockIdx.x * 256 + threadIdx.x;
  if (i >= total4) return;
  size_t base = (size_t)i * 4;
  int c = (int)(base & 255);
  bf16x4 vb = *(const bf16x4*)(cb + base);
  float4 vs = *(const float4*)(out + base);
  float4 r;
  r.x = fmaxf((float)vb[0] * scB[c + 0] + shB[c + 0] + vs.x * scS[c + 0] + shS[c + 0], 0.f);
  r.y = fmaxf((float)vb[1] * scB[c + 1] + shB[c + 1] + vs.y * scS[c + 1] + shS[c + 1], 0.f);
  r.z = fmaxf((float)vb[2] * scB[c + 2] + shB[c + 2] + vs.z * scS[c + 2] + shS[c + 2], 0.f);
  r.w = fmaxf((float)vb[3] * scB[c + 3] + shB[c + 3] + vs.w * scS[c + 3] + shS[c + 3], 0.f);
  *(float4*)(out + base) = r;
}

__global__ void sentinel_k(float* __restrict__ out, int n) {
  int i = blockIdx.x * 256 + threadIdx.x;
  if (i < n) out[i] = 12345.0f;
}

// ---------------- launch ----------------

extern "C" void kernel_launch(void* const* d_in, const int* in_sizes, int n_in,
                              void* d_out, int out_size, void* d_ws, size_t ws_size,
                              hipStream_t stream) {
  const float* x  = (const float*)d_in[0];
  const int* ei   = (const int*)d_in[1];
  const int* etp  = (const int*)d_in[2];
  const float* Wa = (const float*)d_in[4];
  const float* ga = (const float*)d_in[5];
  const float* ba = (const float*)d_in[6];
  const float* Wb = (const float*)d_in[7];
  const float* gb = (const float*)d_in[8];
  const float* bb = (const float*)d_in[9];
  const float* W1 = (const float*)d_in[10];
  const float* g1 = (const float*)d_in[11];
  const float* b1 = (const float*)d_in[12];

  const int C1 = 128, C2 = 256;
  const int N = in_sizes[0] / C1;   // 100000
  const int E = in_sizes[2];        // 700000
  const int* row = ei;
  const int* col = ei + E;
  const int NS = N * N_ET;
  const int KA = N_ET * C1;         // 896
  const int KB = N_ET * C2;         // 1792

  size_t need = 0;
  auto alloc = [&](size_t bytes) { size_t o = need; need += (bytes + 15) & ~(size_t)15; return o; };
  char* w = (char*)d_ws;
  int*   off_p = (int*)(w + alloc(((size_t)NS + 1) * 4));
  int*   cnt_p = (int*)(w + alloc((size_t)NS * 4));
  int*   pcol  = (int*)(w + alloc((size_t)E * 4));
  float* inv_p = (float*)(w + alloc((size_t)NS * 4));
  int*   bsum  = (int*)(w + alloc(1024 * 4));
  bf16*  Bt8A  = (bf16*)(w + alloc((size_t)KA * 256 * 2));
  bf16*  Bt8B  = (bf16*)(w + alloc((size_t)KB * 256 * 2));
  bf16*  Bt1   = (bf16*)(w + alloc((size_t)256 * C1 * 2));
  bf16*  x1    = (bf16*)(w + alloc((size_t)N * C2 * 2));
  bf16*  convb = (bf16*)(w + alloc((size_t)N * C2 * 2));
  float* st    = (float*)(w + alloc(12 * 256 * 4));

  if (ws_size < need) {
    sentinel_k<<<(out_size + 255) / 256, 256, 0, stream>>>((float*)d_out, out_size);
    return;
  }

  float* sum_a = st + 0 * 256, *ssq_a = st + 1 * 256;
  float* sum_b = st + 2 * 256, *ssq_b = st + 3 * 256;
  float* sum_s = st + 4 * 256, *ssq_s = st + 5 * 256;
  float* scA = st + 6 * 256, *shA = st + 7 * 256;
  float* scB = st + 8 * 256, *shB = st + 9 * 256;
  float* scS = st + 10 * 256, *shS = st + 11 * 256;

  const float invN = 1.0f / (float)N;
  const int nscan = (NS + 1023) / 1024;
  const int g2 = (N + 63) / 64;          // fused grid (64-row tiles)
  const int gsc = (N + 127) / 128;       // shortcut grid
  const int total8 = N * C2 / 8;
  const int total4 = N * C2 / 4;

  // --- CSR build ---
  hipMemsetAsync(cnt_p, 0, (size_t)NS * 4, stream);
  hipMemsetAsync(st, 0, 12 * 256 * 4, stream);
  count_edges_k<<<(E + 255) / 256, 256, 0, stream>>>(row, etp, cnt_p, E);
  inv_counts_k<<<(NS + 255) / 256, 256, 0, stream>>>(cnt_p, inv_p, NS);
  scan1_k<<<nscan, 1024, 0, stream>>>(cnt_p, off_p, bsum, NS);
  scan2_k<<<1, 1024, 0, stream>>>(bsum, nscan);
  scan3_k<<<nscan, 1024, 0, stream>>>(off_p, bsum, NS, E);
  hipMemsetAsync(cnt_p, 0, (size_t)NS * 4, stream);
  place_k<<<(E + 255) / 256, 256, 0, stream>>>(row, col, etp, off_p, cnt_p, pcol, E);

  // --- weight transposes ---
  transpose_w8_k<<<(KA * 256 + 255) / 256, 256, 0, stream>>>(Wa, Bt8A, KA);
  transpose_w8_k<<<(KB * 256 + 255) / 256, 256, 0, stream>>>(Wb, Bt8B, KB);
  transpose_w_k<<<(C1 * 256 + 255) / 256, 256, 0, stream>>>(W1, Bt1, C1);

  // --- conv_a: fused-v6 -> x1 (pre-BN bf16), then BN+ReLU in place ---
  agg_gemm6_k<128, float><<<g2, 512, 0, stream>>>(x, Bt8A, off_p, pcol, inv_p, x1, N);
  colstats_bf16_k<<<512, 256, 0, stream>>>(x1, N, sum_a, ssq_a);
  bn_params_k<<<1, 256, 0, stream>>>(sum_a, ssq_a, ga, ba, scA, shA, invN);
  bn_relu_ip_k<<<(total8 + 255) / 256, 256, 0, stream>>>(x1, scA, shA, total8);

  // --- shortcut: x @ W1 -> d_out (f32) ---
  sc_gemm_k<<<gsc, 256, 0, stream>>>(x, Bt1, (float*)d_out, N, C1);
  colstats_f32_k<<<512, 256, 0, stream>>>((const float*)d_out, N, sum_s, ssq_s);
  bn_params_k<<<1, 256, 0, stream>>>(sum_s, ssq_s, g1, b1, scS, shS, invN);

  // --- conv_b: fused-v6 from x1 -> convb (pre-BN bf16) ---
  agg_gemm6_k<256, bf16><<<g2, 512, 0, stream>>>(x1, Bt8B, off_p, pcol, inv_p, convb, N);
  colstats_bf16_k<<<512, 256, 0, stream>>>(convb, N, sum_b, ssq_b);
  bn_params_k<<<1, 256, 0, stream>>>(sum_b, ssq_b, gb, bb, scB, shB, invN);

  // --- out = relu(bn(convb) + bn(scp)) ---
  final_out_k<<<(total4 + 255) / 256, 256, 0, stream>>>(
      convb, scB, shB, scS, shS, (float*)d_out, total4);
}